// Round 6
// baseline (338.707 us; speedup 1.0000x reference)
//
#include <hip/hip_runtime.h>
#include <math.h>

#define B_ 4
#define S_ 2048
#define E_ 1024
#define H_ 16
#define D_ 64
#define MTOT (B_*S_)

typedef _Float16 half8v __attribute__((ext_vector_type(8)));
typedef _Float16 half4v __attribute__((ext_vector_type(4)));
typedef float f32x4 __attribute__((ext_vector_type(4)));
typedef float f32x16 __attribute__((ext_vector_type(16)));
typedef unsigned uint4v __attribute__((ext_vector_type(4)));

typedef __attribute__((address_space(1))) const void gconst_void;
typedef __attribute__((address_space(3))) void lds_void;

#define MFMA16(a,b,c) __builtin_amdgcn_mfma_f32_16x16x32_f16((a),(b),(c),0,0,0)
#define MFMA32(a,b,c) __builtin_amdgcn_mfma_f32_32x32x16_f16((a),(b),(c),0,0,0)

#define QSCALE 0.18033688011112042f  /* 0.125 * log2(e): folded into Q at projection */

// pack two f32 -> u32 of 2 f16 (RTZ)
static __device__ __forceinline__ unsigned cvt_pk_u32(float a, float b) {
  return __builtin_bit_cast(unsigned, __builtin_amdgcn_cvt_pkrtz(a, b));
}

// {lo', hi'} = cross-half swap: lo' = {A.lo, B.lo}, hi' = {A.hi, B.hi}
#if __has_builtin(__builtin_amdgcn_permlane32_swap)
static __device__ __forceinline__ void pl32_swap(unsigned a, unsigned b,
                                                 unsigned& rlo, unsigned& rhi) {
  auto r = __builtin_amdgcn_permlane32_swap(a, b, false, false);
  rlo = r[0]; rhi = r[1];
}
#else
static __device__ __forceinline__ void pl32_swap(unsigned a, unsigned b,
                                                 unsigned& rlo, unsigned& rhi) {
  const int hi = (threadIdx.x & 63) >> 5;
  unsigned t = __shfl_xor(hi ? a : b, 32);
  rlo = hi ? t : a;
  rhi = hi ? b : t;
}
#endif

// partner-lane (lane^32) value of v
static __device__ __forceinline__ float partner32(float v, int hi) {
  unsigned u = __builtin_bit_cast(unsigned, v);
  unsigned lo_, hi_;
  pl32_swap(u, u, lo_, hi_);
  return __builtin_bit_cast(float, hi ? lo_ : hi_);
}

// ---------------- fp32 -> fp16 convert ----------------
__global__ __launch_bounds__(256) void cvt_f32_f16(const float* __restrict__ in,
                                                   _Float16* __restrict__ out, int n) {
  int i = (blockIdx.x * 256 + threadIdx.x) * 4;
  if (i >= n) return;
  float4 v = *(const float4*)(in + i);
  half4v o;
  o[0] = (_Float16)v.x; o[1] = (_Float16)v.y; o[2] = (_Float16)v.z; o[3] = (_Float16)v.w;
  *(half4v*)(out + i) = o;
}

// ---------------- mask prep (format auto-detect) ----------------
__global__ __launch_bounds__(1024) void mask_prep(const unsigned char* __restrict__ mraw,
                                                  _Float16* __restrict__ maskH,
                                                  float* __restrict__ qmask) {
  __shared__ int flags[2];
  const int tid = threadIdx.x;
  if (tid < 2) flags[tid] = 1;
  __syncthreads();
  const unsigned int* w = (const unsigned int*)mraw;
  for (int i = tid; i < 2048; i += 1024) {
    unsigned int v = w[i];
    if (!(v == 0u || v == 1u)) flags[0] = 0;
    if (!(v == 0u || v == 0x3f800000u)) flags[1] = 0;
  }
  __syncthreads();
  const int is_i32 = flags[0], is_f32 = flags[1];
  for (int i = tid; i < B_ * S_; i += 1024) {
    int mv;
    if (is_i32)      mv = ((const int*)mraw)[i];
    else if (is_f32) mv = (((const unsigned int*)mraw)[i] != 0u);
    else             mv = (mraw[i] != 0);
    maskH[i]  = mv ? (_Float16)0.0f : (_Float16)(-60000.0f);
    qmask[i]  = mv ? 1.0f : 0.0f;
  }
}

// ---------------- GEMM staging: 128 rows x 32 f16 cols -> LDS (linear) ----------------
__device__ __forceinline__ void stage128x32(const _Float16* __restrict__ g, int ld,
                                            _Float16* lds, int wid, int lane) {
#pragma unroll
  for (int j = 0; j < 2; ++j) {
    const int c = j * 256 + wid * 64 + lane;
    const _Float16* src = g + (size_t)(c >> 2) * ld + (c & 3) * 8;
    _Float16* dst = lds + (size_t)(j * 256 + wid * 64) * 8;
    __builtin_amdgcn_global_load_lds((gconst_void*)src, (lds_void*)dst, 16, 0, 0);
  }
}

// ---------------- QKV projection GEMM ----------------
// Q stored row-major (B,H,S,D), PRE-SCALED by QSCALE (softmax in log2 domain).
// K stored FRAGMENT-LINEAR: Kf[bh][s>>5][d>>4][s&31][d&15]
// V stored FRAGMENT-LINEAR: Vf[bh][s>>4][d][s&15]
__global__ __launch_bounds__(256) void qkv_gemm(
    const _Float16* __restrict__ xh,
    const _Float16* __restrict__ wq, const _Float16* __restrict__ wk, const _Float16* __restrict__ wv,
    const float* __restrict__ bq, const float* __restrict__ bkp, const float* __restrict__ bvp,
    _Float16* __restrict__ Qh, _Float16* __restrict__ Kh, _Float16* __restrict__ Vth) {
  __shared__ _Float16 As[128 * 32];
  __shared__ _Float16 Bs[128 * 32];
  const int tid = threadIdx.x, lane = tid & 63, wid = tid >> 6;
  const int g = lane >> 4, r16 = lane & 15;
  const int bm = blockIdx.x * 128, bn = blockIdx.y * 128;
  const int z = blockIdx.z;
  const _Float16* w = (z == 0) ? wq : (z == 1) ? wk : wv;
  const float* bias = (z == 0) ? bq : (z == 1) ? bkp : bvp;
  const int wr = wid >> 1, wc = wid & 1;
  f32x4 acc[4][4] = {};
  for (int k0 = 0; k0 < E_; k0 += 32) {
    stage128x32(xh + (size_t)bm * E_ + k0, E_, As, wid, lane);
    stage128x32(w + (size_t)bn * E_ + k0, E_, Bs, wid, lane);
    __syncthreads();
    half8v a[4], bf[4];
#pragma unroll
    for (int i = 0; i < 4; ++i) a[i] = *(const half8v*)&As[(wr * 64 + i * 16 + r16) * 32 + g * 8];
#pragma unroll
    for (int i = 0; i < 4; ++i) bf[i] = *(const half8v*)&Bs[(wc * 64 + i * 16 + r16) * 32 + g * 8];
#pragma unroll
    for (int i = 0; i < 4; ++i)
#pragma unroll
      for (int j = 0; j < 4; ++j) acc[i][j] = MFMA16(a[i], bf[j], acc[i][j]);
    __syncthreads();
  }
#pragma unroll
  for (int i = 0; i < 4; ++i) {
#pragma unroll
    for (int j = 0; j < 4; ++j) {
      const int gn = bn + wc * 64 + j * 16 + r16;
      const float bb = bias[gn];
      const int h = gn >> 6, d = gn & 63;
      const int gm0 = bm + wr * 64 + i * 16 + g * 4;
      const int bb_ = gm0 >> 11, s0 = gm0 & (S_ - 1);
      const size_t bhbase = (size_t)(bb_ * H_ + h) * S_ * D_;
      if (z == 2) {
        half4v v4;
#pragma unroll
        for (int ii = 0; ii < 4; ++ii) v4[ii] = (_Float16)(acc[i][j][ii] + bb);
        *(half4v*)&Vth[bhbase + (size_t)(s0 >> 4) * (D_ * 16) + d * 16 + (s0 & 15)] = v4;
      } else if (z == 1) {
#pragma unroll
        for (int ii = 0; ii < 4; ++ii) {
          const int s = s0 + ii;
          Kh[bhbase + (size_t)(s >> 5) * 2048 + (d >> 4) * 512 + (s & 31) * 16 + (d & 15)] =
              (_Float16)(acc[i][j][ii] + bb);
        }
      } else {
#pragma unroll
        for (int ii = 0; ii < 4; ++ii)
          Qh[bhbase + (size_t)(s0 + ii) * D_ + d] = (_Float16)((acc[i][j][ii] + bb) * QSCALE);
      }
    }
  }
}

// ---------------- flash attention v4: k-split x2, permlane softmax, native exp2 ----------------
// 512 threads = 8 waves: wave = (khalf<<2)|qgroup. Each wave: 32 q rows, half the S loop.
// End merge (m,l,O) via LDS between khalf pairs.
__global__ __launch_bounds__(512, 5) void attn_kernel(
    const _Float16* __restrict__ Qh, const _Float16* __restrict__ Kh, const _Float16* __restrict__ Vth,
    const _Float16* __restrict__ maskH, _Float16* __restrict__ Oh) {
  __shared__ float mlds[4][64][36];  // [qgroup][lane][o32,m,l] from khalf=1 waves
  const int tid = threadIdx.x, lane = tid & 63, wid = tid >> 6;
  const int c = lane & 31, hi = lane >> 5;
  const int qg = wid & 3, kh = wid >> 2;
  const int b = blockIdx.z, h = blockIdx.y;
  const int qw = blockIdx.x * 128 + qg * 32;
  const size_t bh = (size_t)(b * H_ + h);
  const _Float16* Qb = Qh + bh * S_ * D_;
  const _Float16* Kb = Kh + bh * S_ * D_;
  const _Float16* Vb = Vth + bh * S_ * D_;
  const _Float16* mb = maskH + (size_t)b * S_;

  // Q B-frags (pre-scaled): col=q=c, kdim d = 16*kc + 8*hi + j
  half8v qb[4];
#pragma unroll
  for (int kc = 0; kc < 4; ++kc)
    qb[kc] = *(const half8v*)&Qb[(size_t)(qw + c) * D_ + 16 * kc + 8 * hi];

  half8v bone = {};
  if (hi == 0) bone[0] = (_Float16)1.0f;  // B[kdim=0][q]=1 for rank-1 mask MFMA
  const f32x16 fzero = {};

  f32x16 oacc[2] = {};  // out^T[d][q]
  float mrun = -1e30f, lrun = 0.f;
  const int laneoff = c * 16 + 8 * hi;
  const int kb0 = kh * (S_ / 2);

  for (int kb = kb0; kb < kb0 + S_ / 2; kb += 64) {
    // ---- QK^T (swapped, log2 domain): sc[kt] = S^T[k][q] ----
    f32x16 sc[2];
#pragma unroll
    for (int kt = 0; kt < 2; ++kt) {
      half8v amask = {};
      _Float16 mv = mb[kb + 32 * kt + c];
      if (hi == 0) amask[0] = mv;
      const _Float16* kt_base = Kb + (size_t)((kb >> 5) + kt) * 2048 + laneoff;
      __builtin_amdgcn_s_setprio(1);
      f32x16 acc = MFMA32(amask, bone, fzero);
#pragma unroll
      for (int kc = 0; kc < 4; ++kc) {
        half8v ka = *(const half8v*)&kt_base[kc * 512];
        acc = MFMA32(ka, qb[kc], acc);
      }
      __builtin_amdgcn_s_setprio(0);
      sc[kt] = acc;
    }
    // ---- row max: 4 parallel chains + cross-half ----
    float t0 = fmaxf(sc[0][0], sc[1][0]), t1 = fmaxf(sc[0][1], sc[1][1]);
    float t2 = fmaxf(sc[0][2], sc[1][2]), t3 = fmaxf(sc[0][3], sc[1][3]);
#pragma unroll
    for (int r = 4; r < 16; r += 4) {
      t0 = fmaxf(t0, fmaxf(sc[0][r + 0], sc[1][r + 0]));
      t1 = fmaxf(t1, fmaxf(sc[0][r + 1], sc[1][r + 1]));
      t2 = fmaxf(t2, fmaxf(sc[0][r + 2], sc[1][r + 2]));
      t3 = fmaxf(t3, fmaxf(sc[0][r + 3], sc[1][r + 3]));
    }
    float pmax = fmaxf(fmaxf(t0, t1), fmaxf(t2, t3));
    pmax = fmaxf(pmax, partner32(pmax, hi));
    // ---- defer-max rescale (T13, log2 units) ----
    if (__any(pmax > mrun + 11.0f)) {
      float mnew = fmaxf(mrun, pmax);
      float corr = __builtin_amdgcn_exp2f(mrun - mnew);
      mrun = mnew;
      lrun *= corr;
#pragma unroll
      for (int dt = 0; dt < 2; ++dt)
#pragma unroll
        for (int r = 0; r < 16; ++r) oacc[dt][r] *= corr;
    }
    // ---- exp2 + row sum (4 parallel chains) ----
    float s0 = 0.f, s1 = 0.f, s2 = 0.f, s3 = 0.f;
#pragma unroll
    for (int kt = 0; kt < 2; ++kt)
#pragma unroll
      for (int r = 0; r < 16; r += 4) {
        float p0 = __builtin_amdgcn_exp2f(sc[kt][r + 0] - mrun);
        float p1 = __builtin_amdgcn_exp2f(sc[kt][r + 1] - mrun);
        float p2 = __builtin_amdgcn_exp2f(sc[kt][r + 2] - mrun);
        float p3 = __builtin_amdgcn_exp2f(sc[kt][r + 3] - mrun);
        sc[kt][r + 0] = p0; sc[kt][r + 1] = p1; sc[kt][r + 2] = p2; sc[kt][r + 3] = p3;
        s0 += p0; s1 += p1; s2 += p2; s3 += p3;
      }
    float psum = (s0 + s1) + (s2 + s3);
    lrun += psum + partner32(psum, hi);
    // ---- P^T -> f16 B-frags via permlane32_swap (zero-select repack) + PV ----
#pragma unroll
    for (int kc = 0; kc < 4; ++kc) {
      const int kt = kc >> 1, bs = 8 * (kc & 1);
      unsigned uA = cvt_pk_u32(sc[kt][bs + 0], sc[kt][bs + 1]);
      unsigned uB = cvt_pk_u32(sc[kt][bs + 2], sc[kt][bs + 3]);
      unsigned uC = cvt_pk_u32(sc[kt][bs + 4], sc[kt][bs + 5]);
      unsigned uD = cvt_pk_u32(sc[kt][bs + 6], sc[kt][bs + 7]);
      unsigned w0, w1, w2, w3;
      pl32_swap(uA, uC, w0, w2);
      pl32_swap(uB, uD, w1, w3);
      uint4v u4 = {w0, w1, w2, w3};
      const _Float16* v_base = Vb + (size_t)(kb >> 4) * (D_ * 16) + laneoff + kc * (D_ * 16);
      half8v pb = __builtin_bit_cast(half8v, u4);
      half8v va0 = *(const half8v*)&v_base[0];
      half8v va1 = *(const half8v*)&v_base[512];
      __builtin_amdgcn_s_setprio(1);
      oacc[0] = MFMA32(va0, pb, oacc[0]);
      oacc[1] = MFMA32(va1, pb, oacc[1]);
      __builtin_amdgcn_s_setprio(0);
    }
  }
  // ---- k-split merge: khalf=1 publishes, khalf=0 merges + writes ----
  if (kh == 1) {
    float* p = &mlds[qg][lane][0];
#pragma unroll
    for (int dt = 0; dt < 2; ++dt)
#pragma unroll
      for (int rr = 0; rr < 4; ++rr) {
        float4 v4 = make_float4(oacc[dt][4 * rr], oacc[dt][4 * rr + 1],
                                oacc[dt][4 * rr + 2], oacc[dt][4 * rr + 3]);
        *(float4*)&p[dt * 16 + rr * 4] = v4;
      }
    p[32] = mrun;
    p[33] = lrun;
  }
  __syncthreads();
  if (kh == 0) {
    const float* p = &mlds[qg][lane][0];
    const float mB = p[32], lB = p[33];
    const float mS = fmaxf(mrun, mB);
    const float cA = __builtin_amdgcn_exp2f(mrun - mS);
    const float cB = __builtin_amdgcn_exp2f(mB - mS);
    const float inv = 1.0f / (lrun * cA + lB * cB);
    const float fA = cA * inv, fB = cB * inv;
    _Float16* orow = Oh + ((size_t)(b * S_ + qw + c)) * E_ + h * D_;
#pragma unroll
    for (int dt = 0; dt < 2; ++dt)
#pragma unroll
      for (int rr = 0; rr < 4; ++rr) {
        float4 vB = *(const float4*)&p[dt * 16 + rr * 4];
        half4v o4;
        o4[0] = (_Float16)(oacc[dt][4 * rr + 0] * fA + vB.x * fB);
        o4[1] = (_Float16)(oacc[dt][4 * rr + 1] * fA + vB.y * fB);
        o4[2] = (_Float16)(oacc[dt][4 * rr + 2] * fA + vB.z * fB);
        o4[3] = (_Float16)(oacc[dt][4 * rr + 3] * fA + vB.w * fB);
        *(half4v*)&orow[32 * dt + 8 * rr + 4 * hi] = o4;
      }
  }
}

// ---------------- output projection + abs(o*mask), fp32 out ----------------
__global__ __launch_bounds__(256) void oproj_gemm(
    const _Float16* __restrict__ Oh, const _Float16* __restrict__ wo, const float* __restrict__ bo,
    const float* __restrict__ qmask, float* __restrict__ out) {
  __shared__ _Float16 As[128 * 32];
  __shared__ _Float16 Bs[128 * 32];
  const int tid = threadIdx.x, lane = tid & 63, wid = tid >> 6;
  const int g = lane >> 4, r16 = lane & 15;
  const int bm = blockIdx.x * 128, bn = blockIdx.y * 128;
  const int wr = wid >> 1, wc = wid & 1;
  f32x4 acc[4][4] = {};
  for (int k0 = 0; k0 < E_; k0 += 32) {
    stage128x32(Oh + (size_t)bm * E_ + k0, E_, As, wid, lane);
    stage128x32(wo + (size_t)bn * E_ + k0, E_, Bs, wid, lane);
    __syncthreads();
    half8v a[4], bf[4];
#pragma unroll
    for (int i = 0; i < 4; ++i) a[i] = *(const half8v*)&As[(wr * 64 + i * 16 + r16) * 32 + g * 8];
#pragma unroll
    for (int i = 0; i < 4; ++i) bf[i] = *(const half8v*)&Bs[(wc * 64 + i * 16 + r16) * 32 + g * 8];
#pragma unroll
    for (int i = 0; i < 4; ++i)
#pragma unroll
      for (int j = 0; j < 4; ++j) acc[i][j] = MFMA16(a[i], bf[j], acc[i][j]);
    __syncthreads();
  }
#pragma unroll
  for (int i = 0; i < 4; ++i) {
#pragma unroll
    for (int j = 0; j < 4; ++j) {
      const int gn = bn + wc * 64 + j * 16 + r16;
      const float bb = bo[gn];
      const int gm0 = bm + wr * 64 + i * 16 + g * 4;
#pragma unroll
      for (int ii = 0; ii < 4; ++ii) {
        const int gm = gm0 + ii;
        const float y = acc[i][j][ii] + bb;
        out[(size_t)gm * E_ + gn] = fabsf(y * qmask[gm]);
      }
    }
  }
}

extern "C" void kernel_launch(void* const* d_in, const int* in_sizes, int n_in,
                              void* d_out, int out_size, void* d_ws, size_t ws_size,
                              hipStream_t stream) {
  const float* x = (const float*)d_in[0];
  const unsigned char* mask = (const unsigned char*)d_in[1];
  const float* WQ_w = (const float*)d_in[2];
  const float* WQ_b = (const float*)d_in[3];
  const float* WK_w = (const float*)d_in[4];
  const float* WK_b = (const float*)d_in[5];
  const float* WV_w = (const float*)d_in[6];
  const float* WV_b = (const float*)d_in[7];
  const float* WO_w = (const float*)d_in[8];
  const float* WO_b = (const float*)d_in[9];

  char* ws = (char*)d_ws;
  size_t off = 0;
  _Float16* xh  = (_Float16*)(ws + off); off += (size_t)MTOT * E_ * 2;  // reused as O after attn
  _Float16* wqh = (_Float16*)(ws + off); off += (size_t)E_ * E_ * 2;
  _Float16* wkh = (_Float16*)(ws + off); off += (size_t)E_ * E_ * 2;
  _Float16* wvh = (_Float16*)(ws + off); off += (size_t)E_ * E_ * 2;
  _Float16* woh = (_Float16*)(ws + off); off += (size_t)E_ * E_ * 2;
  _Float16* Qh  = (_Float16*)(ws + off); off += (size_t)MTOT * E_ * 2;
  _Float16* Kh  = (_Float16*)(ws + off); off += (size_t)MTOT * E_ * 2;
  _Float16* Vth = (_Float16*)(ws + off); off += (size_t)MTOT * E_ * 2;
  _Float16* maskHf = (_Float16*)(ws + off); off += (size_t)B_ * S_ * 2;
  float* qmaskf   = (float*)(ws + off); off += (size_t)B_ * S_ * 4;
  if (ws_size < off) return;

  const int NX = MTOT * E_;   // 8388608
  const int NW = E_ * E_;     // 1048576
  cvt_f32_f16<<<dim3(NX / 4 / 256), dim3(256), 0, stream>>>(x, xh, NX);
  cvt_f32_f16<<<dim3(NW / 4 / 256), dim3(256), 0, stream>>>(WQ_w, wqh, NW);
  cvt_f32_f16<<<dim3(NW / 4 / 256), dim3(256), 0, stream>>>(WK_w, wkh, NW);
  cvt_f32_f16<<<dim3(NW / 4 / 256), dim3(256), 0, stream>>>(WV_w, wvh, NW);
  cvt_f32_f16<<<dim3(NW / 4 / 256), dim3(256), 0, stream>>>(WO_w, woh, NW);
  mask_prep<<<dim3(1), dim3(1024), 0, stream>>>(mask, maskHf, qmaskf);
  qkv_gemm<<<dim3(MTOT / 128, E_ / 128, 3), dim3(256), 0, stream>>>(
      xh, wqh, wkh, wvh, WQ_b, WK_b, WV_b, Qh, Kh, Vth);
  attn_kernel<<<dim3(S_ / 128, H_, B_), dim3(512), 0, stream>>>(Qh, Kh, Vth, maskHf, xh);
  oproj_gemm<<<dim3(MTOT / 128, E_ / 128), dim3(256), 0, stream>>>(xh, woh, WO_b, qmaskf, (float*)d_out);
}

// Round 7
// 234.293 us; speedup vs baseline: 1.4457x; 1.4457x over previous
//
#include <hip/hip_runtime.h>
#include <math.h>

#define B_ 4
#define S_ 2048
#define E_ 1024
#define H_ 16
#define D_ 64
#define MTOT (B_*S_)

typedef _Float16 half8v __attribute__((ext_vector_type(8)));
typedef _Float16 half4v __attribute__((ext_vector_type(4)));
typedef float f32x4 __attribute__((ext_vector_type(4)));
typedef float f32x16 __attribute__((ext_vector_type(16)));
typedef unsigned uint4v __attribute__((ext_vector_type(4)));

typedef __attribute__((address_space(1))) const void gconst_void;
typedef __attribute__((address_space(3))) void lds_void;

#define MFMA16(a,b,c) __builtin_amdgcn_mfma_f32_16x16x32_f16((a),(b),(c),0,0,0)
#define MFMA32(a,b,c) __builtin_amdgcn_mfma_f32_32x32x16_f16((a),(b),(c),0,0,0)

#define QSCALE 0.18033688011112042f  /* 0.125 * log2(e): folded into Q at projection */

// pack two f32 -> u32 of 2 f16 (RTZ)
static __device__ __forceinline__ unsigned cvt_pk_u32(float a, float b) {
  return __builtin_bit_cast(unsigned, __builtin_amdgcn_cvt_pkrtz(a, b));
}

// {lo', hi'} = cross-half swap: lo' = {A.lo, B.lo}, hi' = {A.hi, B.hi}
#if __has_builtin(__builtin_amdgcn_permlane32_swap)
static __device__ __forceinline__ void pl32_swap(unsigned a, unsigned b,
                                                 unsigned& rlo, unsigned& rhi) {
  auto r = __builtin_amdgcn_permlane32_swap(a, b, false, false);
  rlo = r[0]; rhi = r[1];
}
#else
static __device__ __forceinline__ void pl32_swap(unsigned a, unsigned b,
                                                 unsigned& rlo, unsigned& rhi) {
  const int hi = (threadIdx.x & 63) >> 5;
  unsigned t = __shfl_xor(hi ? a : b, 32);
  rlo = hi ? t : a;
  rhi = hi ? b : t;
}
#endif

// partner-lane (lane^32) value of v
static __device__ __forceinline__ float partner32(float v, int hi) {
  unsigned u = __builtin_bit_cast(unsigned, v);
  unsigned lo_, hi_;
  pl32_swap(u, u, lo_, hi_);
  return __builtin_bit_cast(float, hi ? lo_ : hi_);
}

// ---------------- fp32 -> fp16 convert ----------------
__global__ __launch_bounds__(256) void cvt_f32_f16(const float* __restrict__ in,
                                                   _Float16* __restrict__ out, int n) {
  int i = (blockIdx.x * 256 + threadIdx.x) * 4;
  if (i >= n) return;
  float4 v = *(const float4*)(in + i);
  half4v o;
  o[0] = (_Float16)v.x; o[1] = (_Float16)v.y; o[2] = (_Float16)v.z; o[3] = (_Float16)v.w;
  *(half4v*)(out + i) = o;
}

// ---------------- mask prep (format auto-detect) ----------------
__global__ __launch_bounds__(1024) void mask_prep(const unsigned char* __restrict__ mraw,
                                                  _Float16* __restrict__ maskH,
                                                  float* __restrict__ qmask) {
  __shared__ int flags[2];
  const int tid = threadIdx.x;
  if (tid < 2) flags[tid] = 1;
  __syncthreads();
  const unsigned int* w = (const unsigned int*)mraw;
  for (int i = tid; i < 2048; i += 1024) {
    unsigned int v = w[i];
    if (!(v == 0u || v == 1u)) flags[0] = 0;
    if (!(v == 0u || v == 0x3f800000u)) flags[1] = 0;
  }
  __syncthreads();
  const int is_i32 = flags[0], is_f32 = flags[1];
  for (int i = tid; i < B_ * S_; i += 1024) {
    int mv;
    if (is_i32)      mv = ((const int*)mraw)[i];
    else if (is_f32) mv = (((const unsigned int*)mraw)[i] != 0u);
    else             mv = (mraw[i] != 0);
    maskH[i]  = mv ? (_Float16)0.0f : (_Float16)(-60000.0f);
    qmask[i]  = mv ? 1.0f : 0.0f;
  }
}

// ---------------- GEMM staging: 128 rows x 32 f16 cols -> LDS (linear) ----------------
__device__ __forceinline__ void stage128x32(const _Float16* __restrict__ g, int ld,
                                            _Float16* lds, int wid, int lane) {
#pragma unroll
  for (int j = 0; j < 2; ++j) {
    const int c = j * 256 + wid * 64 + lane;
    const _Float16* src = g + (size_t)(c >> 2) * ld + (c & 3) * 8;
    _Float16* dst = lds + (size_t)(j * 256 + wid * 64) * 8;
    __builtin_amdgcn_global_load_lds((gconst_void*)src, (lds_void*)dst, 16, 0, 0);
  }
}

// ---------------- QKV projection GEMM ----------------
// Q stored row-major (B,H,S,D), PRE-SCALED by QSCALE (softmax in log2 domain).
// K stored FRAGMENT-LINEAR: Kf[bh][s>>5][d>>4][s&31][d&15]
// V stored FRAGMENT-LINEAR: Vf[bh][s>>4][d][s&15]
__global__ __launch_bounds__(256) void qkv_gemm(
    const _Float16* __restrict__ xh,
    const _Float16* __restrict__ wq, const _Float16* __restrict__ wk, const _Float16* __restrict__ wv,
    const float* __restrict__ bq, const float* __restrict__ bkp, const float* __restrict__ bvp,
    _Float16* __restrict__ Qh, _Float16* __restrict__ Kh, _Float16* __restrict__ Vth) {
  __shared__ _Float16 As[128 * 32];
  __shared__ _Float16 Bs[128 * 32];
  const int tid = threadIdx.x, lane = tid & 63, wid = tid >> 6;
  const int g = lane >> 4, r16 = lane & 15;
  const int bm = blockIdx.x * 128, bn = blockIdx.y * 128;
  const int z = blockIdx.z;
  const _Float16* w = (z == 0) ? wq : (z == 1) ? wk : wv;
  const float* bias = (z == 0) ? bq : (z == 1) ? bkp : bvp;
  const int wr = wid >> 1, wc = wid & 1;
  f32x4 acc[4][4] = {};
  for (int k0 = 0; k0 < E_; k0 += 32) {
    stage128x32(xh + (size_t)bm * E_ + k0, E_, As, wid, lane);
    stage128x32(w + (size_t)bn * E_ + k0, E_, Bs, wid, lane);
    __syncthreads();
    half8v a[4], bf[4];
#pragma unroll
    for (int i = 0; i < 4; ++i) a[i] = *(const half8v*)&As[(wr * 64 + i * 16 + r16) * 32 + g * 8];
#pragma unroll
    for (int i = 0; i < 4; ++i) bf[i] = *(const half8v*)&Bs[(wc * 64 + i * 16 + r16) * 32 + g * 8];
#pragma unroll
    for (int i = 0; i < 4; ++i)
#pragma unroll
      for (int j = 0; j < 4; ++j) acc[i][j] = MFMA16(a[i], bf[j], acc[i][j]);
    __syncthreads();
  }
#pragma unroll
  for (int i = 0; i < 4; ++i) {
#pragma unroll
    for (int j = 0; j < 4; ++j) {
      const int gn = bn + wc * 64 + j * 16 + r16;
      const float bb = bias[gn];
      const int h = gn >> 6, d = gn & 63;
      const int gm0 = bm + wr * 64 + i * 16 + g * 4;
      const int bb_ = gm0 >> 11, s0 = gm0 & (S_ - 1);
      const size_t bhbase = (size_t)(bb_ * H_ + h) * S_ * D_;
      if (z == 2) {
        half4v v4;
#pragma unroll
        for (int ii = 0; ii < 4; ++ii) v4[ii] = (_Float16)(acc[i][j][ii] + bb);
        *(half4v*)&Vth[bhbase + (size_t)(s0 >> 4) * (D_ * 16) + d * 16 + (s0 & 15)] = v4;
      } else if (z == 1) {
#pragma unroll
        for (int ii = 0; ii < 4; ++ii) {
          const int s = s0 + ii;
          Kh[bhbase + (size_t)(s >> 5) * 2048 + (d >> 4) * 512 + (s & 31) * 16 + (d & 15)] =
              (_Float16)(acc[i][j][ii] + bb);
        }
      } else {
#pragma unroll
        for (int ii = 0; ii < 4; ++ii)
          Qh[bhbase + (size_t)(s0 + ii) * D_ + d] = (_Float16)((acc[i][j][ii] + bb) * QSCALE);
      }
    }
  }
}

// ---------------- flash attention v4b: k-split x2, natural register budget ----------------
// 512 threads = 8 waves: wave = (khalf<<2)|qgroup. Each wave: 32 q rows, half the S loop.
// End merge (m,l,O) via LDS between khalf pairs.
__global__ __launch_bounds__(512) void attn_kernel(
    const _Float16* __restrict__ Qh, const _Float16* __restrict__ Kh, const _Float16* __restrict__ Vth,
    const _Float16* __restrict__ maskH, _Float16* __restrict__ Oh) {
  __shared__ float mlds[4][64][36];  // [qgroup][lane][o32,m,l] from khalf=1 waves
  const int tid = threadIdx.x, lane = tid & 63, wid = tid >> 6;
  const int c = lane & 31, hi = lane >> 5;
  const int qg = wid & 3, kh = wid >> 2;
  const int b = blockIdx.z, h = blockIdx.y;
  const int qw = blockIdx.x * 128 + qg * 32;
  const size_t bh = (size_t)(b * H_ + h);
  const _Float16* Qb = Qh + bh * S_ * D_;
  const _Float16* Kb = Kh + bh * S_ * D_;
  const _Float16* Vb = Vth + bh * S_ * D_;
  const _Float16* mb = maskH + (size_t)b * S_;

  // Q B-frags (pre-scaled): col=q=c, kdim d = 16*kc + 8*hi + j
  half8v qb[4];
#pragma unroll
  for (int kc = 0; kc < 4; ++kc)
    qb[kc] = *(const half8v*)&Qb[(size_t)(qw + c) * D_ + 16 * kc + 8 * hi];

  half8v bone = {};
  if (hi == 0) bone[0] = (_Float16)1.0f;  // B[kdim=0][q]=1 for rank-1 mask MFMA
  const f32x16 fzero = {};

  f32x16 oacc[2] = {};  // out^T[d][q]
  float mrun = -1e30f, lrun = 0.f;
  const int laneoff = c * 16 + 8 * hi;
  const int kb0 = kh * (S_ / 2);

  for (int kb = kb0; kb < kb0 + S_ / 2; kb += 64) {
    // ---- QK^T (swapped, log2 domain): sc[kt] = S^T[k][q] ----
    f32x16 sc[2];
#pragma unroll
    for (int kt = 0; kt < 2; ++kt) {
      half8v amask = {};
      _Float16 mv = mb[kb + 32 * kt + c];
      if (hi == 0) amask[0] = mv;
      const _Float16* kt_base = Kb + (size_t)((kb >> 5) + kt) * 2048 + laneoff;
      __builtin_amdgcn_s_setprio(1);
      f32x16 acc = MFMA32(amask, bone, fzero);
#pragma unroll
      for (int kc = 0; kc < 4; ++kc) {
        half8v ka = *(const half8v*)&kt_base[kc * 512];
        acc = MFMA32(ka, qb[kc], acc);
      }
      __builtin_amdgcn_s_setprio(0);
      sc[kt] = acc;
    }
    // ---- row max: 4 parallel chains + cross-half ----
    float t0 = fmaxf(sc[0][0], sc[1][0]), t1 = fmaxf(sc[0][1], sc[1][1]);
    float t2 = fmaxf(sc[0][2], sc[1][2]), t3 = fmaxf(sc[0][3], sc[1][3]);
#pragma unroll
    for (int r = 4; r < 16; r += 4) {
      t0 = fmaxf(t0, fmaxf(sc[0][r + 0], sc[1][r + 0]));
      t1 = fmaxf(t1, fmaxf(sc[0][r + 1], sc[1][r + 1]));
      t2 = fmaxf(t2, fmaxf(sc[0][r + 2], sc[1][r + 2]));
      t3 = fmaxf(t3, fmaxf(sc[0][r + 3], sc[1][r + 3]));
    }
    float pmax = fmaxf(fmaxf(t0, t1), fmaxf(t2, t3));
    pmax = fmaxf(pmax, partner32(pmax, hi));
    // ---- defer-max rescale (T13, log2 units) ----
    if (__any(pmax > mrun + 11.0f)) {
      float mnew = fmaxf(mrun, pmax);
      float corr = __builtin_amdgcn_exp2f(mrun - mnew);
      mrun = mnew;
      lrun *= corr;
#pragma unroll
      for (int dt = 0; dt < 2; ++dt)
#pragma unroll
        for (int r = 0; r < 16; ++r) oacc[dt][r] *= corr;
    }
    // ---- exp2 + row sum (4 parallel chains) ----
    float s0 = 0.f, s1 = 0.f, s2 = 0.f, s3 = 0.f;
#pragma unroll
    for (int kt = 0; kt < 2; ++kt)
#pragma unroll
      for (int r = 0; r < 16; r += 4) {
        float p0 = __builtin_amdgcn_exp2f(sc[kt][r + 0] - mrun);
        float p1 = __builtin_amdgcn_exp2f(sc[kt][r + 1] - mrun);
        float p2 = __builtin_amdgcn_exp2f(sc[kt][r + 2] - mrun);
        float p3 = __builtin_amdgcn_exp2f(sc[kt][r + 3] - mrun);
        sc[kt][r + 0] = p0; sc[kt][r + 1] = p1; sc[kt][r + 2] = p2; sc[kt][r + 3] = p3;
        s0 += p0; s1 += p1; s2 += p2; s3 += p3;
      }
    float psum = (s0 + s1) + (s2 + s3);
    lrun += psum + partner32(psum, hi);
    // ---- P^T -> f16 B-frags via permlane32_swap (zero-select repack) + PV ----
#pragma unroll
    for (int kc = 0; kc < 4; ++kc) {
      const int kt = kc >> 1, bs = 8 * (kc & 1);
      unsigned uA = cvt_pk_u32(sc[kt][bs + 0], sc[kt][bs + 1]);
      unsigned uB = cvt_pk_u32(sc[kt][bs + 2], sc[kt][bs + 3]);
      unsigned uC = cvt_pk_u32(sc[kt][bs + 4], sc[kt][bs + 5]);
      unsigned uD = cvt_pk_u32(sc[kt][bs + 6], sc[kt][bs + 7]);
      unsigned w0, w1, w2, w3;
      pl32_swap(uA, uC, w0, w2);
      pl32_swap(uB, uD, w1, w3);
      uint4v u4 = {w0, w1, w2, w3};
      const _Float16* v_base = Vb + (size_t)(kb >> 4) * (D_ * 16) + laneoff + kc * (D_ * 16);
      half8v pb = __builtin_bit_cast(half8v, u4);
      half8v va0 = *(const half8v*)&v_base[0];
      half8v va1 = *(const half8v*)&v_base[512];
      __builtin_amdgcn_s_setprio(1);
      oacc[0] = MFMA32(va0, pb, oacc[0]);
      oacc[1] = MFMA32(va1, pb, oacc[1]);
      __builtin_amdgcn_s_setprio(0);
    }
  }
  // ---- k-split merge: khalf=1 publishes, khalf=0 merges + writes ----
  if (kh == 1) {
    float* p = &mlds[qg][lane][0];
#pragma unroll
    for (int dt = 0; dt < 2; ++dt)
#pragma unroll
      for (int rr = 0; rr < 4; ++rr) {
        float4 v4 = make_float4(oacc[dt][4 * rr], oacc[dt][4 * rr + 1],
                                oacc[dt][4 * rr + 2], oacc[dt][4 * rr + 3]);
        *(float4*)&p[dt * 16 + rr * 4] = v4;
      }
    p[32] = mrun;
    p[33] = lrun;
  }
  __syncthreads();
  if (kh == 0) {
    const float* p = &mlds[qg][lane][0];
    const float mB = p[32], lB = p[33];
    const float mS = fmaxf(mrun, mB);
    const float cA = __builtin_amdgcn_exp2f(mrun - mS);
    const float cB = __builtin_amdgcn_exp2f(mB - mS);
    const float inv = 1.0f / (lrun * cA + lB * cB);
    const float fA = cA * inv, fB = cB * inv;
    _Float16* orow = Oh + ((size_t)(b * S_ + qw + c)) * E_ + h * D_;
#pragma unroll
    for (int dt = 0; dt < 2; ++dt)
#pragma unroll
      for (int rr = 0; rr < 4; ++rr) {
        float4 vB = *(const float4*)&p[dt * 16 + rr * 4];
        half4v o4;
        o4[0] = (_Float16)(oacc[dt][4 * rr + 0] * fA + vB.x * fB);
        o4[1] = (_Float16)(oacc[dt][4 * rr + 1] * fA + vB.y * fB);
        o4[2] = (_Float16)(oacc[dt][4 * rr + 2] * fA + vB.z * fB);
        o4[3] = (_Float16)(oacc[dt][4 * rr + 3] * fA + vB.w * fB);
        *(half4v*)&orow[32 * dt + 8 * rr + 4 * hi] = o4;
      }
  }
}

// ---------------- output projection + abs(o*mask), fp32 out ----------------
__global__ __launch_bounds__(256) void oproj_gemm(
    const _Float16* __restrict__ Oh, const _Float16* __restrict__ wo, const float* __restrict__ bo,
    const float* __restrict__ qmask, float* __restrict__ out) {
  __shared__ _Float16 As[128 * 32];
  __shared__ _Float16 Bs[128 * 32];
  const int tid = threadIdx.x, lane = tid & 63, wid = tid >> 6;
  const int g = lane >> 4, r16 = lane & 15;
  const int bm = blockIdx.x * 128, bn = blockIdx.y * 128;
  const int wr = wid >> 1, wc = wid & 1;
  f32x4 acc[4][4] = {};
  for (int k0 = 0; k0 < E_; k0 += 32) {
    stage128x32(Oh + (size_t)bm * E_ + k0, E_, As, wid, lane);
    stage128x32(wo + (size_t)bn * E_ + k0, E_, Bs, wid, lane);
    __syncthreads();
    half8v a[4], bf[4];
#pragma unroll
    for (int i = 0; i < 4; ++i) a[i] = *(const half8v*)&As[(wr * 64 + i * 16 + r16) * 32 + g * 8];
#pragma unroll
    for (int i = 0; i < 4; ++i) bf[i] = *(const half8v*)&Bs[(wc * 64 + i * 16 + r16) * 32 + g * 8];
#pragma unroll
    for (int i = 0; i < 4; ++i)
#pragma unroll
      for (int j = 0; j < 4; ++j) acc[i][j] = MFMA16(a[i], bf[j], acc[i][j]);
    __syncthreads();
  }
#pragma unroll
  for (int i = 0; i < 4; ++i) {
#pragma unroll
    for (int j = 0; j < 4; ++j) {
      const int gn = bn + wc * 64 + j * 16 + r16;
      const float bb = bo[gn];
      const int gm0 = bm + wr * 64 + i * 16 + g * 4;
#pragma unroll
      for (int ii = 0; ii < 4; ++ii) {
        const int gm = gm0 + ii;
        const float y = acc[i][j][ii] + bb;
        out[(size_t)gm * E_ + gn] = fabsf(y * qmask[gm]);
      }
    }
  }
}

extern "C" void kernel_launch(void* const* d_in, const int* in_sizes, int n_in,
                              void* d_out, int out_size, void* d_ws, size_t ws_size,
                              hipStream_t stream) {
  const float* x = (const float*)d_in[0];
  const unsigned char* mask = (const unsigned char*)d_in[1];
  const float* WQ_w = (const float*)d_in[2];
  const float* WQ_b = (const float*)d_in[3];
  const float* WK_w = (const float*)d_in[4];
  const float* WK_b = (const float*)d_in[5];
  const float* WV_w = (const float*)d_in[6];
  const float* WV_b = (const float*)d_in[7];
  const float* WO_w = (const float*)d_in[8];
  const float* WO_b = (const float*)d_in[9];

  char* ws = (char*)d_ws;
  size_t off = 0;
  _Float16* xh  = (_Float16*)(ws + off); off += (size_t)MTOT * E_ * 2;  // reused as O after attn
  _Float16* wqh = (_Float16*)(ws + off); off += (size_t)E_ * E_ * 2;
  _Float16* wkh = (_Float16*)(ws + off); off += (size_t)E_ * E_ * 2;
  _Float16* wvh = (_Float16*)(ws + off); off += (size_t)E_ * E_ * 2;
  _Float16* woh = (_Float16*)(ws + off); off += (size_t)E_ * E_ * 2;
  _Float16* Qh  = (_Float16*)(ws + off); off += (size_t)MTOT * E_ * 2;
  _Float16* Kh  = (_Float16*)(ws + off); off += (size_t)MTOT * E_ * 2;
  _Float16* Vth = (_Float16*)(ws + off); off += (size_t)MTOT * E_ * 2;
  _Float16* maskHf = (_Float16*)(ws + off); off += (size_t)B_ * S_ * 2;
  float* qmaskf   = (float*)(ws + off); off += (size_t)B_ * S_ * 4;
  if (ws_size < off) return;

  const int NX = MTOT * E_;   // 8388608
  const int NW = E_ * E_;     // 1048576
  cvt_f32_f16<<<dim3(NX / 4 / 256), dim3(256), 0, stream>>>(x, xh, NX);
  cvt_f32_f16<<<dim3(NW / 4 / 256), dim3(256), 0, stream>>>(WQ_w, wqh, NW);
  cvt_f32_f16<<<dim3(NW / 4 / 256), dim3(256), 0, stream>>>(WK_w, wkh, NW);
  cvt_f32_f16<<<dim3(NW / 4 / 256), dim3(256), 0, stream>>>(WV_w, wvh, NW);
  cvt_f32_f16<<<dim3(NW / 4 / 256), dim3(256), 0, stream>>>(WO_w, woh, NW);
  mask_prep<<<dim3(1), dim3(1024), 0, stream>>>(mask, maskHf, qmaskf);
  qkv_gemm<<<dim3(MTOT / 128, E_ / 128, 3), dim3(256), 0, stream>>>(
      xh, wqh, wkh, wvh, WQ_b, WK_b, WV_b, Qh, Kh, Vth);
  attn_kernel<<<dim3(S_ / 128, H_, B_), dim3(512), 0, stream>>>(Qh, Kh, Vth, maskHf, xh);
  oproj_gemm<<<dim3(MTOT / 128, E_ / 128), dim3(256), 0, stream>>>(xh, woh, WO_b, qmaskf, (float*)d_out);
}